// Round 1
// 26546.671 us; speedup vs baseline: 3.6195x; 3.6195x over previous
//
#include <hip/hip_runtime.h>
#include <math.h>

// Problem dims (fixed by reference)
#define BB 32
#define SS 512
#define VV 30522
#define EE 768
#define HH 768
#define TT 9
#define G4 (4*HH)   // 3072
#define NBLK 96     // persistent LSTM grid: 96 blocks <= 256 CUs, co-resident

// ---------------------------------------------------------------------------
// Embedding gather: x[row][:] = emb[ids[row]][:]
__global__ void embed_kernel(const int* __restrict__ ids,
                             const float* __restrict__ emb,
                             float* __restrict__ x) {
    const int row = blockIdx.x;
    const int e4  = threadIdx.x;           // 0..191
    const int id  = ids[row];
    *(float4*)&x[(size_t)row * EE + e4 * 4] =
        *(const float4*)&emb[(size_t)id * EE + e4 * 4];
}

// ---------------------------------------------------------------------------
// fp32 GEMM (pure fp32 accumulate, replicating an fp32 numpy reference):
// C[M,N] = A[M,K] @ W[N,K]^T + b1[N] + b2[N]
__global__ __launch_bounds__(256) void gemm_simple(
    const float* __restrict__ A, const float* __restrict__ W,
    const float* __restrict__ bias1, const float* __restrict__ bias2,
    float* __restrict__ C, int M, int N, int K) {
    __shared__ float As[16][65];
    __shared__ float Ws[16][65];
    const int tid = threadIdx.x;
    const int tx = tid & 15, ty = tid >> 4;
    const int m0 = blockIdx.y * 64, n0 = blockIdx.x * 64;
    float acc[4][4];
    #pragma unroll
    for (int i = 0; i < 4; ++i)
        #pragma unroll
        for (int j = 0; j < 4; ++j) acc[i][j] = 0.f;

    for (int k0 = 0; k0 < K; k0 += 16) {
        #pragma unroll
        for (int i = 0; i < 4; ++i) {
            int r = ty + i * 16;            // 0..63
            As[tx][r] = A[(size_t)(m0 + r) * K + k0 + tx];
            Ws[tx][r] = W[(size_t)(n0 + r) * K + k0 + tx];
        }
        __syncthreads();
        #pragma unroll
        for (int kk = 0; kk < 16; ++kk) {
            float ar[4], br[4];
            #pragma unroll
            for (int i = 0; i < 4; ++i) ar[i] = As[kk][ty * 4 + i];
            #pragma unroll
            for (int j = 0; j < 4; ++j) br[j] = Ws[kk][tx * 4 + j];
            #pragma unroll
            for (int i = 0; i < 4; ++i)
                #pragma unroll
                for (int j = 0; j < 4; ++j) acc[i][j] += ar[i] * br[j];
        }
        __syncthreads();
    }
    #pragma unroll
    for (int i = 0; i < 4; ++i) {
        int r = m0 + ty * 4 + i;
        #pragma unroll
        for (int j = 0; j < 4; ++j) {
            int c = n0 + tx * 4 + j;
            C[(size_t)r * N + c] = acc[i][j] + bias1[c] + bias2[c];
        }
    }
}

// ---------------------------------------------------------------------------
// Pack Whh [3072,768] into wpk[u][k][g]: wpk[(u*768+k)*4+g] = Whh[(g*768+u)*768+k]
__global__ __launch_bounds__(256) void pack_whh(const float* __restrict__ Whh,
                                                float* __restrict__ wpk) {
    const int id = blockIdx.x * 256 + threadIdx.x;   // over 768*768
    const int u = id / 768;
    const int k = id - u * 768;
    float4 o;
    o.x = Whh[(size_t)(0 * 768 + u) * 768 + k];
    o.y = Whh[(size_t)(1 * 768 + u) * 768 + k];
    o.z = Whh[(size_t)(2 * 768 + u) * 768 + k];
    o.w = Whh[(size_t)(3 * 768 + u) * 768 + k];
    *(float4*)&wpk[(size_t)id * 4] = o;
}

// ---------------------------------------------------------------------------
// Zero the grid-barrier counters (must run each launch / graph replay).
__global__ void init_bars(unsigned* __restrict__ bar) {
    if (threadIdx.x < 2) bar[threadIdx.x] = 0u;
}

// ---------------------------------------------------------------------------
// Persistent full-layer LSTM, PURE fp32, one launch per layer.
//   grid = 96 blocks x 256 threads, 1 block/CU (128 KB dynamic LDS).
//   Thread (ul=tid&7, b=tid>>3) owns the 4-gate dot for (u = blk*8+ul, b)
//   for ALL 512 timesteps; cell state c lives in a register.
//   Whh slice (8 u x 4 g x 768 k = 96 KB) is loaded into LDS ONCE,
//   as float4 at index k*8+ul  -> a wave's 8 distinct 16B reads cover all
//   32 banks exactly once (conflict-free, 8-way broadcast).
//   h_{t-1} staged from global in 256-k chunks into a 32 KB LDS buffer
//   (same exact fp32 accumulation order as the previous per-step kernel).
//   Steps separated by a hand-rolled grid barrier: monotonic device-scope
//   counter, target (t+1)*NBLK (no reset -> no reuse races).
__global__ __launch_bounds__(256) void lstm_layer_persist(
    const float* __restrict__ xW,    // [B*S*3072] input proj + biases
    const float* __restrict__ wpk,   // [768*768*4] packed Whh
    float* __restrict__ h_out,       // [B*S*768]
    float* __restrict__ hTa,         // ping [768*32], [u*32+b]
    float* __restrict__ hTb,         // pong
    unsigned* __restrict__ bar) {    // one zeroed counter
    extern __shared__ float smem[];
    float4* wlds = (float4*)smem;            // 6144 float4 = 96 KB
    float*  hs   = smem + 24576;             // 8192 floats = 32 KB
    const int tid = threadIdx.x;
    const int ul = tid & 7;
    const int b  = tid >> 3;
    const int u  = blockIdx.x * 8 + ul;

    // one-time weight stage: wlds[k*8+uu] = wpk4[(blk*8+uu)*768 + k]
    const float4* wp4 = (const float4*)wpk;
    for (int idx = tid; idx < 6144; idx += 256) {
        int k  = idx >> 3;
        int uu = idx & 7;
        wlds[idx] = wp4[(size_t)(blockIdx.x * 8 + uu) * 768 + k];
    }
    __syncthreads();

    float c = 0.f;
    for (int t = 0; t < SS; ++t) {
        const size_t row = (size_t)b * SS + t;
        // issue xW loads early; latency hides under the matvec
        float gi = xW[row * G4 + 0 * HH + u];
        float gf = xW[row * G4 + 1 * HH + u];
        float gg = xW[row * G4 + 2 * HH + u];
        float go = xW[row * G4 + 3 * HH + u];

        if (t > 0) {
            const float* hin = (t & 1) ? hTb : hTa;
            float a0 = 0.f, a1 = 0.f, a2 = 0.f, a3 = 0.f;
            for (int k0 = 0; k0 < 768; k0 += 256) {
                __syncthreads();             // protect hs reuse
                const float4* src = (const float4*)(hin + k0 * 32);
                float4* dst = (float4*)hs;
                #pragma unroll
                for (int r = 0; r < 8; ++r) dst[r * 256 + tid] = src[r * 256 + tid];
                __syncthreads();
                const float4* wp = wlds + k0 * 8 + ul;
                #pragma unroll 8
                for (int kk = 0; kk < 256; ++kk) {
                    float hv = hs[kk * 32 + b];
                    float4 wv = wp[kk * 8];
                    a0 += wv.x * hv; a1 += wv.y * hv;
                    a2 += wv.z * hv; a3 += wv.w * hv;
                }
            }
            gi += a0; gf += a1; gg += a2; go += a3;
        }

        float si = 1.f / (1.f + expf(-gi));
        float sf = 1.f / (1.f + expf(-gf));
        float so = 1.f / (1.f + expf(-go));
        float tg = tanhf(gg);
        c = sf * c + si * tg;                // t=0: c starts at 0
        float h = so * tanhf(c);
        h_out[row * HH + u] = h;
        float* hout = (t & 1) ? hTa : hTb;   // step t writes hbuf[(t+1)&1]
        hout[u * 32 + b] = h;

        if (t < SS - 1) {
            // grid barrier: all blocks must finish step t before t+1
            __syncthreads();                 // drains this block's stores
            if (tid == 0) {
                __builtin_amdgcn_fence(__ATOMIC_RELEASE, "agent");
                atomicAdd(bar, 1u);          // device scope by default
                const unsigned target = (unsigned)(t + 1) * NBLK;
                while (__hip_atomic_load(bar, __ATOMIC_RELAXED,
                                         __HIP_MEMORY_SCOPE_AGENT) < target)
                    __builtin_amdgcn_s_sleep(1);
                __builtin_amdgcn_fence(__ATOMIC_ACQUIRE, "agent");
            }
            __syncthreads();
        }
    }
}

// ---------------------------------------------------------------------------
// Scalar logits + log_softmax, pure fp32, one thread per row.
__global__ __launch_bounds__(256) void logits_kernel(
    const float* __restrict__ h, const float* __restrict__ Wout,
    const float* __restrict__ bout, float* __restrict__ logp) {
    const int row = blockIdx.x * 256 + threadIdx.x;   // 0..16383
    const float* hr = &h[(size_t)row * HH];
    float lg[TT];
    for (int tt = 0; tt < TT; ++tt) {
        const float* wr = &Wout[tt * HH];
        float ps = 0.f;
        for (int k = 0; k < HH; ++k) ps += hr[k] * wr[k];
        lg[tt] = ps + bout[tt];
    }
    float mx = lg[0];
    for (int tt = 1; tt < TT; ++tt) mx = fmaxf(mx, lg[tt]);
    float sm = 0.f;
    for (int tt = 0; tt < TT; ++tt) sm += expf(lg[tt] - mx);
    float lse = mx + logf(sm);
    for (int tt = 0; tt < TT; ++tt) logp[(size_t)row * TT + tt] = lg[tt] - lse;
}

// ---------------------------------------------------------------------------
// CRF forward (loss), pure fp32: wave per batch, lanes = next-tag. 32 blocks.
#define NEG_INF_F -3.0e38f
__global__ __launch_bounds__(64) void crf_forward(
    const float* __restrict__ logp, const int* __restrict__ labels,
    const int* __restrict__ mask, const float* __restrict__ start_t,
    const float* __restrict__ end_t, const float* __restrict__ trans,
    float* __restrict__ bstats) {
    const int b = blockIdx.x;
    const int lane = threadIdx.x;
    const int j = lane < TT ? lane : TT - 1;
    const float* em = logp + (size_t)b * SS * TT;
    const int* mk = mask + b * SS;
    const int* lb = labels + b * SS;
    float tr[TT];
    #pragma unroll
    for (int i = 0; i < TT; ++i) tr[i] = trans[i * TT + j];
    float sc = start_t[j] + em[j];

    for (int t = 1; t < SS; ++t) {
        const int m = mk[t];
        const float e = em[t * TT + j];
        float v[TT];
        #pragma unroll
        for (int i = 0; i < TT; ++i) v[i] = __shfl(sc, i) + tr[i];
        float mx = v[0];
        #pragma unroll
        for (int i = 1; i < TT; ++i) mx = fmaxf(mx, v[i]);
        float smv = 0.f;
        #pragma unroll
        for (int i = 0; i < TT; ++i) smv += expf(v[i] - mx);
        float nxt = mx + logf(smv) + e;
        sc = m ? nxt : sc;
    }
    float fin = sc + end_t[j];
    float fv[TT];
    #pragma unroll
    for (int i = 0; i < TT; ++i) fv[i] = __shfl(fin, i);
    float mx = fv[0];
    #pragma unroll
    for (int i = 1; i < TT; ++i) mx = fmaxf(mx, fv[i]);
    float smv = 0.f;
    #pragma unroll
    for (int i = 0; i < TT; ++i) smv += expf(fv[i] - mx);
    float denom = mx + logf(smv);
    // numerator + token count
    float np = 0.f; int ic = 0;
    for (int t = lane; t < SS; t += 64) {
        int m = mk[t];
        ic += m;
        if (t > 0 && m) {
            int tg = lb[t], tp = lb[t - 1];
            np += trans[tp * TT + tg] + em[t * TT + tg];
        }
    }
    for (int off = 32; off; off >>= 1) {
        np += __shfl_down(np, off);
        ic += __shfl_down(ic, off);
    }
    if (lane == 0) {
        int tg0 = lb[0];
        np += start_t[tg0] + em[tg0];
        int tgl = lb[ic - 1];              // mask is a contiguous prefix
        np += end_t[tgl];
        bstats[b * 3 + 0] = np;
        bstats[b * 3 + 1] = denom;
        bstats[b * 3 + 2] = (float)ic;
    }
}

// ---------------------------------------------------------------------------
// Fully scalar Viterbi decode, pure fp32: one thread per batch.
__global__ __launch_bounds__(64) void crf_decode(
    const float* __restrict__ logp, const int* __restrict__ mask,
    const float* __restrict__ start_t, const float* __restrict__ end_t,
    const float* __restrict__ trans, float* __restrict__ preds) {
    __shared__ unsigned char bp[SS][TT];
    if (threadIdx.x != 0) return;
    const int b = blockIdx.x;
    const float* em = logp + (size_t)b * SS * TT;
    const int* mk = mask + b * SS;
    float sc[TT], nx[TT];
    for (int jj = 0; jj < TT; ++jj) sc[jj] = start_t[jj] + em[jj];

    for (int t = 1; t < SS; ++t) {
        const int m = mk[t];
        for (int jj = 0; jj < TT; ++jj) {
            float bmv = NEG_INF_F; int bi = 0;
            for (int i = 0; i < TT; ++i) {
                float v = sc[i] + trans[i * TT + jj];
                if (v > bmv) { bmv = v; bi = i; }     // first max wins
            }
            nx[jj] = bmv + em[t * TT + jj];
            bp[t][jj] = (unsigned char)(m ? bi : jj); // identity when masked
        }
        if (m) for (int jj = 0; jj < TT; ++jj) sc[jj] = nx[jj];
    }
    float bm = NEG_INF_F; int best = 0;
    for (int jj = 0; jj < TT; ++jj) {
        float v = sc[jj] + end_t[jj];
        if (v > bm) { bm = v; best = jj; }
    }
    int tag = best;
    preds[b * SS + (SS - 1)] = (float)(mk[SS - 1] ? tag : 0);
    for (int t = SS - 1; t >= 1; --t) {
        tag = bp[t][tag];
        preds[b * SS + t - 1] = (float)(mk[t - 1] ? tag : 0);
    }
}

__global__ void loss_kernel(const float* __restrict__ bstats,
                            float* __restrict__ out) {
    const int lane = threadIdx.x;
    float nd = 0.f, c = 0.f;
    if (lane < 32) {
        nd = bstats[lane * 3] - bstats[lane * 3 + 1];
        c  = bstats[lane * 3 + 2];
    }
    for (int off = 32; off; off >>= 1) {
        nd += __shfl_down(nd, off);
        c  += __shfl_down(c, off);
    }
    if (lane == 0) out[0] = -nd / c;
}

// ---------------------------------------------------------------------------
extern "C" void kernel_launch(void* const* d_in, const int* in_sizes, int n_in,
                              void* d_out, int out_size, void* d_ws, size_t ws_size,
                              hipStream_t stream) {
    const int*   ids   = (const int*)d_in[0];
    const int*   amask = (const int*)d_in[1];
    const int*   labels= (const int*)d_in[2];
    const float* emb   = (const float*)d_in[3];
    const float* Wih0  = (const float*)d_in[4];
    const float* Whh0  = (const float*)d_in[5];
    const float* bih0  = (const float*)d_in[6];
    const float* bhh0  = (const float*)d_in[7];
    const float* Wih1  = (const float*)d_in[8];
    const float* Whh1  = (const float*)d_in[9];
    const float* bih1  = (const float*)d_in[10];
    const float* bhh1  = (const float*)d_in[11];
    const float* Wout  = (const float*)d_in[12];
    const float* boutp = (const float*)d_in[13];
    const float* st    = (const float*)d_in[14];
    const float* et    = (const float*)d_in[15];
    const float* trp   = (const float*)d_in[16];

    // workspace layout (floats). Same known-good footprint as before;
    // the old cbuf slot is reused for the two grid-barrier counters.
    float* ws     = (float*)d_ws;
    float* slab   = ws;                       // 12,582,912 (x / h0 / h1)
    float* xW     = slab + 12582912;          // 50,331,648 (gate pre-acts)
    float* hTa    = xW + 50331648;            // 24,576 (ping)
    float* hTb    = hTa + 24576;              // 24,576 (pong)
    float* wpk    = hTb + 24576;              // 2,359,296
    float* cb     = wpk + 2359296;            // 24,576 (FREE: barrier counters)
    float* logp   = cb + 24576;               // 147,456
    float* bstats = logp + 147456;            // 96
    unsigned* bar = (unsigned*)cb;
    float* out    = (float*)d_out;

    // allow 128 KB dynamic LDS for the persistent kernel (1 block/CU)
    static bool attr_done = false;
    if (!attr_done) {
        hipFuncSetAttribute((const void*)lstm_layer_persist,
                            hipFuncAttributeMaxDynamicSharedMemorySize,
                            131072);
        attr_done = true;
    }

    dim3 ggrid(G4 / 64, (BB * SS) / 64);      // (48, 256)

    init_bars<<<1, 64, 0, stream>>>(bar);

    // layer 0
    embed_kernel<<<BB * SS, EE / 4, 0, stream>>>(ids, emb, slab);
    gemm_simple<<<ggrid, 256, 0, stream>>>(slab, Wih0, bih0, bhh0, xW,
                                           BB * SS, G4, EE);
    pack_whh<<<(HH * HH) / 256, 256, 0, stream>>>(Whh0, wpk);
    lstm_layer_persist<<<NBLK, 256, 131072, stream>>>(xW, wpk, slab,
                                                      hTa, hTb, bar + 0);

    // layer 1
    gemm_simple<<<ggrid, 256, 0, stream>>>(slab, Wih1, bih1, bhh1, xW,
                                           BB * SS, G4, HH);
    pack_whh<<<(HH * HH) / 256, 256, 0, stream>>>(Whh1, wpk);
    lstm_layer_persist<<<NBLK, 256, 131072, stream>>>(xW, wpk, slab,
                                                      hTa, hTb, bar + 1);

    // projection + log_softmax (scalar fp32)
    logits_kernel<<<(BB * SS) / 256, 256, 0, stream>>>(slab, Wout, boutp, logp);

    // CRF loss + scalar decode (fp32)
    crf_forward<<<32, 64, 0, stream>>>(logp, labels, amask, st, et, trp, bstats);
    crf_decode<<<32, 64, 0, stream>>>(logp, amask, st, et, trp, out + 1);
    loss_kernel<<<1, 64, 0, stream>>>(bstats, out);
}